// Round 1
// baseline (858.468 us; speedup 1.0000x reference)
//
#include <hip/hip_runtime.h>

#define N_NODES 20000
#define E_EDGES 160000
#define ET (E_EDGES + N_NODES)   // 180000 with self-loops
#define IN_CH 128
#define HID 1296
#define HEADS 36
#define CPH 36
#define OUT_CH 128
#define NEG_SLOPE 0.2f

// ---------------- GEMM1: h1[N,1296] = x[N,128] @ W1[128,1296] ----------------
__global__ __launch_bounds__(256) void k_gemm1(const float* __restrict__ x,
                                               const float* __restrict__ W1,
                                               float* __restrict__ h1) {
    __shared__ float xs[32][IN_CH];
    int r0 = blockIdx.x * 32;
    int c0 = blockIdx.y * 256;
    int tid = threadIdx.x;
    for (int i = tid; i < 32 * IN_CH; i += 256) {
        int r = i >> 7, k = i & 127;
        xs[r][k] = x[(size_t)(r0 + r) * IN_CH + k];
    }
    __syncthreads();
    int col = c0 + tid;
    if (col >= HID) return;
    float acc[32];
#pragma unroll
    for (int r = 0; r < 32; r++) acc[r] = 0.f;
#pragma unroll 4
    for (int k = 0; k < IN_CH; k++) {
        float w = W1[(size_t)k * HID + col];
#pragma unroll
        for (int r = 0; r < 32; r++) acc[r] += xs[r][k] * w;
    }
#pragma unroll
    for (int r = 0; r < 32; r++)
        h1[(size_t)(r0 + r) * HID + col] = acc[r];
}

// ---------------- alpha1: per (node,head) dot over 36 channels ----------------
__global__ __launch_bounds__(256) void k_alpha1(const float* __restrict__ h1,
                                                const float* __restrict__ a_src,
                                                const float* __restrict__ a_dst,
                                                float* __restrict__ as,
                                                float* __restrict__ ad) {
    __shared__ float s_a[HEADS * CPH], s_b[HEADS * CPH];
    int tid = threadIdx.x;
    for (int i = tid; i < HEADS * CPH; i += 256) { s_a[i] = a_src[i]; s_b[i] = a_dst[i]; }
    __syncthreads();
    int gid = blockIdx.x * 256 + tid;
    if (gid >= N_NODES * HEADS) return;
    int n = gid / HEADS, h = gid % HEADS;
    const float* row = h1 + (size_t)n * HID + h * CPH;
    float ss = 0.f, sd = 0.f;
#pragma unroll
    for (int c = 0; c < CPH; c++) {
        float v = row[c];
        ss += v * s_a[h * CPH + c];
        sd += v * s_b[h * CPH + c];
    }
    as[gid] = ss;
    ad[gid] = sd;
}

// ---------------- CSR build ----------------
__global__ void k_count(const int* __restrict__ ei, int* __restrict__ cnt) {
    int e = blockIdx.x * 256 + threadIdx.x;
    if (e >= ET) return;
    int d = (e < E_EDGES) ? ei[E_EDGES + e] : (e - E_EDGES);
    atomicAdd(&cnt[d], 1);
}

__global__ __launch_bounds__(1024) void k_scan(const int* __restrict__ cnt, int* __restrict__ rowp) {
    __shared__ int sh[1024];
    const int PER = 20;  // 1024*20 = 20480 >= 20000
    int t = threadIdx.x;
    int base = t * PER;
    int local[PER];
    int sum = 0;
    for (int i = 0; i < PER; i++) {
        int idx = base + i;
        int v = (idx < N_NODES) ? cnt[idx] : 0;
        local[i] = sum;
        sum += v;
    }
    sh[t] = sum;
    __syncthreads();
    for (int off = 1; off < 1024; off <<= 1) {
        int v = (t >= off) ? sh[t - off] : 0;
        __syncthreads();
        sh[t] += v;
        __syncthreads();
    }
    int offset = (t == 0) ? 0 : sh[t - 1];
    for (int i = 0; i < PER; i++) {
        int idx = base + i;
        if (idx < N_NODES) rowp[idx] = offset + local[i];
    }
    if (t == 1023) rowp[N_NODES] = sh[1023];
}

__global__ void k_fill(const int* __restrict__ ei, const int* __restrict__ rowp,
                       int* __restrict__ cursor, int* __restrict__ col) {
    int e = blockIdx.x * 256 + threadIdx.x;
    if (e >= ET) return;
    int s, d;
    if (e < E_EDGES) { s = ei[e]; d = ei[E_EDGES + e]; }
    else { s = e - E_EDGES; d = s; }
    int pos = rowp[d] + atomicAdd(&cursor[d], 1);
    col[pos] = s;
}

// ---------------- agg1: per dst node, softmax + weighted gather ----------------
__global__ __launch_bounds__(256) void k_agg1(const float* __restrict__ h1,
                                              const float* __restrict__ as,
                                              const float* __restrict__ ad,
                                              const int* __restrict__ rowp,
                                              const int* __restrict__ col,
                                              const float* __restrict__ b1,
                                              float* __restrict__ out1) {
    int n = blockIdx.x;
    int tid = threadIdx.x;
    __shared__ float inv_denom[HEADS];
    __shared__ float wsh[HEADS];
    int r0 = rowp[n], r1 = rowp[n + 1];
    // pass 1: softmax denominator per head (no max subtraction; e is bounded, fp32 safe)
    if (tid < HEADS) {
        float adn = ad[(size_t)n * HEADS + tid];
        float den = 0.f;
        for (int e = r0; e < r1; e++) {
            int s = col[e];
            float v = as[(size_t)s * HEADS + tid] + adn;
            v = (v > 0.f) ? v : NEG_SLOPE * v;
            den += __expf(v);
        }
        inv_denom[tid] = 1.f / (den + 1e-16f);
    }
    __syncthreads();
    float acc[6];
#pragma unroll
    for (int j = 0; j < 6; j++) acc[j] = 0.f;
    int hh[6];
#pragma unroll
    for (int j = 0; j < 6; j++) { int c = tid + j * 256; hh[j] = (c < HID) ? c / CPH : 0; }
    float adn_all = (tid < HEADS) ? ad[(size_t)n * HEADS + tid] : 0.f;
    for (int e = r0; e < r1; e++) {
        int s = col[e];
        if (tid < HEADS) {
            float v = as[(size_t)s * HEADS + tid] + adn_all;
            v = (v > 0.f) ? v : NEG_SLOPE * v;
            wsh[tid] = __expf(v) * inv_denom[tid];
        }
        __syncthreads();
        const float* hrow = h1 + (size_t)s * HID;
#pragma unroll
        for (int j = 0; j < 6; j++) {
            int c = tid + j * 256;
            if (c < HID) acc[j] += wsh[hh[j]] * hrow[c];
        }
        __syncthreads();
    }
#pragma unroll
    for (int j = 0; j < 6; j++) {
        int c = tid + j * 256;
        if (c < HID) {
            float v = acc[j] + b1[c];
            out1[(size_t)n * HID + c] = (v > 0.f) ? v : 0.f;
        }
    }
}

// ---------------- GEMM2: h2[N,128] = out1[N,1296] @ W2[1296,128] ----------------
__global__ __launch_bounds__(256) void k_gemm2(const float* __restrict__ out1,
                                               const float* __restrict__ W2,
                                               float* __restrict__ h2) {
    __shared__ float xs[32][64];
    int r0 = blockIdx.x * 32;
    int tid = threadIdx.x;
    int colt = tid & 127;
    int half = tid >> 7;
    float acc[16];
#pragma unroll
    for (int j = 0; j < 16; j++) acc[j] = 0.f;
    for (int k0 = 0; k0 < HID; k0 += 64) {
        __syncthreads();
        for (int i = tid; i < 32 * 64; i += 256) {
            int r = i >> 6, k = i & 63;
            int kk = k0 + k;
            xs[r][k] = (kk < HID) ? out1[(size_t)(r0 + r) * HID + kk] : 0.f;
        }
        __syncthreads();
        int kmax = (HID - k0 < 64) ? (HID - k0) : 64;
#pragma unroll 4
        for (int k = 0; k < kmax; k++) {
            float w = W2[(size_t)(k0 + k) * OUT_CH + colt];
#pragma unroll
            for (int j = 0; j < 16; j++)
                acc[j] += xs[half + 2 * j][k] * w;
        }
    }
#pragma unroll
    for (int j = 0; j < 16; j++)
        h2[(size_t)(r0 + half + 2 * j) * OUT_CH + colt] = acc[j];
}

// ---------------- alpha2: per node dot over 128 channels (1 head) ----------------
__global__ __launch_bounds__(64) void k_alpha2(const float* __restrict__ h2,
                                               const float* __restrict__ a_src,
                                               const float* __restrict__ a_dst,
                                               float* __restrict__ as,
                                               float* __restrict__ ad) {
    int n = blockIdx.x;
    int t = threadIdx.x;
    const float* row = h2 + (size_t)n * OUT_CH;
    float v0 = row[t], v1 = row[t + 64];
    float ss = v0 * a_src[t] + v1 * a_src[t + 64];
    float sd = v0 * a_dst[t] + v1 * a_dst[t + 64];
    for (int off = 32; off > 0; off >>= 1) {
        ss += __shfl_down(ss, off);
        sd += __shfl_down(sd, off);
    }
    if (t == 0) { as[n] = ss; ad[n] = sd; }
}

// ---------------- agg2: per dst node, 1 head, C=128 ----------------
__global__ __launch_bounds__(128) void k_agg2(const float* __restrict__ h2,
                                              const float* __restrict__ as,
                                              const float* __restrict__ ad,
                                              const int* __restrict__ rowp,
                                              const int* __restrict__ col,
                                              const float* __restrict__ b2,
                                              float* __restrict__ out) {
    int n = blockIdx.x;
    int tid = threadIdx.x;
    __shared__ float sh_inv;
    int r0 = rowp[n], r1 = rowp[n + 1];
    float adn = ad[n];
    if (tid < 64) {
        float den = 0.f;
        for (int e = r0 + tid; e < r1; e += 64) {
            int s = col[e];
            float v = as[s] + adn;
            v = (v > 0.f) ? v : NEG_SLOPE * v;
            den += __expf(v);
        }
        for (int off = 32; off > 0; off >>= 1) den += __shfl_down(den, off);
        if (tid == 0) sh_inv = 1.f / (den + 1e-16f);
    }
    __syncthreads();
    float inv = sh_inv;
    float acc = 0.f;
    for (int e = r0; e < r1; e++) {
        int s = col[e];
        float v = as[s] + adn;
        v = (v > 0.f) ? v : NEG_SLOPE * v;
        float w = __expf(v) * inv;
        acc += w * h2[(size_t)s * OUT_CH + tid];
    }
    float v = acc + b2[tid];
    out[(size_t)n * OUT_CH + tid] = (v > 0.f) ? v : 0.f;
}

extern "C" void kernel_launch(void* const* d_in, const int* in_sizes, int n_in,
                              void* d_out, int out_size, void* d_ws, size_t ws_size,
                              hipStream_t stream) {
    const float* x      = (const float*)d_in[0];
    const int*   ei     = (const int*)d_in[1];
    const float* W1     = (const float*)d_in[2];
    const float* a_src1 = (const float*)d_in[3];
    const float* a_dst1 = (const float*)d_in[4];
    const float* b1     = (const float*)d_in[5];
    const float* W2     = (const float*)d_in[6];
    const float* a_src2 = (const float*)d_in[7];
    const float* a_dst2 = (const float*)d_in[8];
    const float* b2     = (const float*)d_in[9];
    float* out = (float*)d_out;

    // workspace layout (floats)
    float* ws = (float*)d_ws;
    float* h1   = ws;                                   // 25,920,000
    float* out1 = h1 + (size_t)N_NODES * HID;           // 25,920,000
    float* as1  = out1 + (size_t)N_NODES * HID;         // 720,000
    float* ad1  = as1 + (size_t)N_NODES * HEADS;        // 720,000
    float* h2   = ad1 + (size_t)N_NODES * HEADS;        // 2,560,000
    float* as2  = h2 + (size_t)N_NODES * OUT_CH;        // 20,000
    float* ad2  = as2 + N_NODES;                        // 20,000
    int* cnt    = (int*)(ad2 + N_NODES);                // 20,000
    int* cursor = cnt + N_NODES;                        // 20,000
    int* rowp   = cursor + N_NODES;                     // 20,001
    int* colx   = rowp + (N_NODES + 1);                 // 180,000

    hipMemsetAsync(cnt, 0, (size_t)2 * N_NODES * sizeof(int), stream);

    k_gemm1<<<dim3(625, 6), 256, 0, stream>>>(x, W1, h1);
    k_alpha1<<<(N_NODES * HEADS + 255) / 256, 256, 0, stream>>>(h1, a_src1, a_dst1, as1, ad1);
    k_count<<<(ET + 255) / 256, 256, 0, stream>>>(ei, cnt);
    k_scan<<<1, 1024, 0, stream>>>(cnt, rowp);
    k_fill<<<(ET + 255) / 256, 256, 0, stream>>>(ei, rowp, cursor, colx);
    k_agg1<<<N_NODES, 256, 0, stream>>>(h1, as1, ad1, rowp, colx, b1, out1);
    k_gemm2<<<625, 256, 0, stream>>>(out1, W2, h2);
    k_alpha2<<<N_NODES, 64, 0, stream>>>(h2, a_src2, a_dst2, as2, ad2);
    k_agg2<<<N_NODES, 128, 0, stream>>>(h2, as2, ad2, rowp, colx, b2, out);
}

// Round 2
// 551.343 us; speedup vs baseline: 1.5570x; 1.5570x over previous
//
#include <hip/hip_runtime.h>

#define N_NODES 20000
#define E_EDGES 160000
#define ET (E_EDGES + N_NODES)   // 180000 with self-loops
#define IN_CH 128
#define HID 1296
#define HEADS 36
#define CPH 36
#define OUT_CH 128
#define NEG_SLOPE 0.2f

// ---------------- GEMM1: h1[N,1296] = x[N,128] @ W1[128,1296] ----------------
// 64x64 tile, 256 threads, 4x4 micro-tile. A staged transposed [k][row].
__global__ __launch_bounds__(256) void k_gemm1(const float* __restrict__ x,
                                               const float* __restrict__ W1,
                                               float* __restrict__ h1) {
    __shared__ float As[32][68];   // [k][row], pad to 68 for write-conflict reduction
    __shared__ float Bs[32][64];   // [k][col]
    int tid = threadIdx.x;
    int r0 = blockIdx.x * 64;
    int c0 = blockIdx.y * 64;
    int ty = tid >> 4, tx = tid & 15;
    float acc[4][4];
#pragma unroll
    for (int i = 0; i < 4; i++)
#pragma unroll
        for (int j = 0; j < 4; j++) acc[i][j] = 0.f;

    for (int k0 = 0; k0 < IN_CH; k0 += 32) {
        __syncthreads();
        {   // stage A (transpose): 64 rows x 32 k
            int k4 = (tid & 7) * 4;
#pragma unroll
            for (int i = 0; i < 2; i++) {
                int r = (tid >> 3) + i * 32;
                int gr = min(r0 + r, N_NODES - 1);
                const float4 v = *(const float4*)(x + (size_t)gr * IN_CH + k0 + k4);
                As[k4 + 0][r] = v.x; As[k4 + 1][r] = v.y;
                As[k4 + 2][r] = v.z; As[k4 + 3][r] = v.w;
            }
        }
        {   // stage B: 32 k x 64 cols
            int c4 = (tid & 15) * 4;
            int gc = min(c0 + c4, HID - 4);
#pragma unroll
            for (int i = 0; i < 2; i++) {
                int kk = (tid >> 4) + i * 16;
                *(float4*)&Bs[kk][c4] = *(const float4*)(W1 + (size_t)(k0 + kk) * HID + gc);
            }
        }
        __syncthreads();
#pragma unroll
        for (int k = 0; k < 32; k++) {
            float4 a = *(const float4*)&As[k][ty * 4];
            float4 b = *(const float4*)&Bs[k][tx * 4];
            float av[4] = {a.x, a.y, a.z, a.w};
            float bv[4] = {b.x, b.y, b.z, b.w};
#pragma unroll
            for (int i = 0; i < 4; i++)
#pragma unroll
                for (int j = 0; j < 4; j++) acc[i][j] += av[i] * bv[j];
        }
    }
#pragma unroll
    for (int i = 0; i < 4; i++) {
        int row = r0 + ty * 4 + i;
        int colc = c0 + tx * 4;
        if (row < N_NODES && colc + 3 < HID) {
            float4 o = {acc[i][0], acc[i][1], acc[i][2], acc[i][3]};
            *(float4*)(h1 + (size_t)row * HID + colc) = o;
        }
    }
}

// ---------------- GEMM2: h2[N,128] = out1[N,1296] @ W2[1296,128] ----------------
__global__ __launch_bounds__(256) void k_gemm2(const float* __restrict__ A,
                                               const float* __restrict__ W2,
                                               float* __restrict__ h2) {
    __shared__ float As[32][68];
    __shared__ float Bs[32][64];
    int tid = threadIdx.x;
    int r0 = blockIdx.x * 64;
    int c0 = blockIdx.y * 64;
    int ty = tid >> 4, tx = tid & 15;
    float acc[4][4];
#pragma unroll
    for (int i = 0; i < 4; i++)
#pragma unroll
        for (int j = 0; j < 4; j++) acc[i][j] = 0.f;

    for (int k0 = 0; k0 < HID; k0 += 32) {   // 41 chunks, last is 16 wide (zero-filled)
        __syncthreads();
        {
            int k4 = (tid & 7) * 4;
#pragma unroll
            for (int i = 0; i < 2; i++) {
                int r = (tid >> 3) + i * 32;
                int gr = min(r0 + r, N_NODES - 1);
                float4 v = {0.f, 0.f, 0.f, 0.f};
                if (k0 + k4 + 3 < HID) v = *(const float4*)(A + (size_t)gr * HID + k0 + k4);
                As[k4 + 0][r] = v.x; As[k4 + 1][r] = v.y;
                As[k4 + 2][r] = v.z; As[k4 + 3][r] = v.w;
            }
        }
        {
            int c4 = (tid & 15) * 4;
#pragma unroll
            for (int i = 0; i < 2; i++) {
                int kk = (tid >> 4) + i * 16;
                float4 v = {0.f, 0.f, 0.f, 0.f};
                if (k0 + kk < HID) v = *(const float4*)(W2 + (size_t)(k0 + kk) * OUT_CH + c0 + c4);
                *(float4*)&Bs[kk][c4] = v;
            }
        }
        __syncthreads();
#pragma unroll
        for (int k = 0; k < 32; k++) {
            float4 a = *(const float4*)&As[k][ty * 4];
            float4 b = *(const float4*)&Bs[k][tx * 4];
            float av[4] = {a.x, a.y, a.z, a.w};
            float bv[4] = {b.x, b.y, b.z, b.w};
#pragma unroll
            for (int i = 0; i < 4; i++)
#pragma unroll
                for (int j = 0; j < 4; j++) acc[i][j] += av[i] * bv[j];
        }
    }
#pragma unroll
    for (int i = 0; i < 4; i++) {
        int row = r0 + ty * 4 + i;
        if (row < N_NODES) {
            float4 o = {acc[i][0], acc[i][1], acc[i][2], acc[i][3]};
            *(float4*)(h2 + (size_t)row * OUT_CH + c0 + tx * 4) = o;
        }
    }
}

// ---------------- alpha1: per (node,head) dot over 36 channels ----------------
__global__ __launch_bounds__(256) void k_alpha1(const float* __restrict__ h1,
                                                const float* __restrict__ a_src,
                                                const float* __restrict__ a_dst,
                                                float* __restrict__ as,
                                                float* __restrict__ ad) {
    __shared__ float s_a[HEADS * CPH], s_b[HEADS * CPH];
    int tid = threadIdx.x;
    for (int i = tid; i < HEADS * CPH; i += 256) { s_a[i] = a_src[i]; s_b[i] = a_dst[i]; }
    __syncthreads();
    int gid = blockIdx.x * 256 + tid;
    if (gid >= N_NODES * HEADS) return;
    int n = gid / HEADS, h = gid - n * HEADS;
    const float* row = h1 + (size_t)n * HID + h * CPH;
    float ss = 0.f, sd = 0.f;
#pragma unroll
    for (int c = 0; c < CPH; c++) {
        float v = row[c];
        ss += v * s_a[h * CPH + c];
        sd += v * s_b[h * CPH + c];
    }
    as[gid] = ss;
    ad[gid] = sd;
}

// ---------------- CSR build ----------------
__global__ void k_count(const int* __restrict__ ei, int* __restrict__ cnt) {
    int e = blockIdx.x * 256 + threadIdx.x;
    if (e >= ET) return;
    int d = (e < E_EDGES) ? ei[E_EDGES + e] : (e - E_EDGES);
    atomicAdd(&cnt[d], 1);
}

__global__ __launch_bounds__(1024) void k_scan(const int* __restrict__ cnt, int* __restrict__ rowp) {
    __shared__ int sh[1024];
    const int PER = 20;  // 1024*20 = 20480 >= 20000
    int t = threadIdx.x;
    int base = t * PER;
    int local[PER];
    int sum = 0;
    for (int i = 0; i < PER; i++) {
        int idx = base + i;
        int v = (idx < N_NODES) ? cnt[idx] : 0;
        local[i] = sum;
        sum += v;
    }
    sh[t] = sum;
    __syncthreads();
    for (int off = 1; off < 1024; off <<= 1) {
        int v = (t >= off) ? sh[t - off] : 0;
        __syncthreads();
        sh[t] += v;
        __syncthreads();
    }
    int offset = (t == 0) ? 0 : sh[t - 1];
    for (int i = 0; i < PER; i++) {
        int idx = base + i;
        if (idx < N_NODES) rowp[idx] = offset + local[i];
    }
    if (t == 1023) rowp[N_NODES] = sh[1023];
}

__global__ void k_fill(const int* __restrict__ ei, const int* __restrict__ rowp,
                       int* __restrict__ cursor, int* __restrict__ col,
                       int* __restrict__ dstn) {
    int e = blockIdx.x * 256 + threadIdx.x;
    if (e >= ET) return;
    int s, d;
    if (e < E_EDGES) { s = ei[e]; d = ei[E_EDGES + e]; }
    else { s = e - E_EDGES; d = s; }
    int pos = rowp[d] + atomicAdd(&cursor[d], 1);
    col[pos] = s;
    dstn[pos] = d;
}

// ---------------- w1: unnormalized softmax numerators per CSR position ----------------
__global__ __launch_bounds__(256) void k_w1(const float* __restrict__ as1,
                                            const float* __restrict__ ad1,
                                            const int* __restrict__ col,
                                            const int* __restrict__ dstn,
                                            float* __restrict__ w) {
    int gid = blockIdx.x * 256 + threadIdx.x;
    if (gid >= ET * HEADS) return;
    int p = gid / HEADS, h = gid - p * HEADS;
    int s = col[p], d = dstn[p];
    float v = as1[(size_t)s * HEADS + h] + ad1[(size_t)d * HEADS + h];
    v = (v > 0.f) ? v : NEG_SLOPE * v;
    w[gid] = __expf(v);
}

// ---------------- agg1: per dst node, normalize + weighted float4 gather ----------------
// 1296 = 324 float4 slots; slot s covers channels 4s..4s+3 which lie in ONE head (s/9).
__global__ __launch_bounds__(256) void k_agg1(const float* __restrict__ h1,
                                              const float* __restrict__ w,
                                              const int* __restrict__ rowp,
                                              const int* __restrict__ col,
                                              const float* __restrict__ b1,
                                              float* __restrict__ out1) {
    int n = blockIdx.x;
    int tid = threadIdx.x;
    int r0 = rowp[n], r1 = rowp[n + 1];
    __shared__ float inv[HEADS];
    __shared__ float wsh[32 * HEADS];
    __shared__ int   csh[32];
    if (tid < HEADS) {
        float den = 0.f;
        for (int p = r0; p < r1; p++) den += w[(size_t)p * HEADS + tid];
        inv[tid] = 1.f / (den + 1e-16f);
    }
    __syncthreads();
    float4 acc0 = {0.f, 0.f, 0.f, 0.f}, acc1 = {0.f, 0.f, 0.f, 0.f};
    int s1 = tid;              // slot 0..255
    int s2 = tid + 256;        // slot 256..323 (only tid<68)
    int h1i = s1 / 9;
    int h2i = (s2 < 324) ? s2 / 9 : 0;
    for (int p0 = r0; p0 < r1; p0 += 32) {
        int ne = min(32, r1 - p0);
        __syncthreads();   // protect wsh/csh from previous chunk's readers
        for (int i = tid; i < ne * HEADS; i += 256) {
            int h = i % HEADS;
            wsh[i] = w[(size_t)p0 * HEADS + i] * inv[h];
        }
        if (tid < ne) csh[tid] = col[p0 + tid];
        __syncthreads();
        for (int e = 0; e < ne; e++) {
            const float4* hr = (const float4*)(h1 + (size_t)csh[e] * HID);
            float wa = wsh[e * HEADS + h1i];
            float4 v1 = hr[s1];
            acc0.x += wa * v1.x; acc0.y += wa * v1.y;
            acc0.z += wa * v1.z; acc0.w += wa * v1.w;
            if (s2 < 324) {
                float wb = wsh[e * HEADS + h2i];
                float4 v2 = hr[s2];
                acc1.x += wb * v2.x; acc1.y += wb * v2.y;
                acc1.z += wb * v2.z; acc1.w += wb * v2.w;
            }
        }
    }
    const float4* b4 = (const float4*)b1;
    float4* o4 = (float4*)(out1 + (size_t)n * HID);
    {
        float4 bb = b4[s1];
        float4 o;
        o.x = fmaxf(acc0.x + bb.x, 0.f); o.y = fmaxf(acc0.y + bb.y, 0.f);
        o.z = fmaxf(acc0.z + bb.z, 0.f); o.w = fmaxf(acc0.w + bb.w, 0.f);
        o4[s1] = o;
    }
    if (s2 < 324) {
        float4 bb = b4[s2];
        float4 o;
        o.x = fmaxf(acc1.x + bb.x, 0.f); o.y = fmaxf(acc1.y + bb.y, 0.f);
        o.z = fmaxf(acc1.z + bb.z, 0.f); o.w = fmaxf(acc1.w + bb.w, 0.f);
        o4[s2] = o;
    }
}

// ---------------- alpha2: per node dot over 128 channels (1 head) ----------------
__global__ __launch_bounds__(64) void k_alpha2(const float* __restrict__ h2,
                                               const float* __restrict__ a_src,
                                               const float* __restrict__ a_dst,
                                               float* __restrict__ as,
                                               float* __restrict__ ad) {
    int n = blockIdx.x;
    int t = threadIdx.x;
    const float* row = h2 + (size_t)n * OUT_CH;
    float v0 = row[t], v1 = row[t + 64];
    float ss = v0 * a_src[t] + v1 * a_src[t + 64];
    float sd = v0 * a_dst[t] + v1 * a_dst[t + 64];
    for (int off = 32; off > 0; off >>= 1) {
        ss += __shfl_down(ss, off);
        sd += __shfl_down(sd, off);
    }
    if (t == 0) { as[n] = ss; ad[n] = sd; }
}

// ---------------- agg2: per dst node, 1 head, C=128 ----------------
__global__ __launch_bounds__(128) void k_agg2(const float* __restrict__ h2,
                                              const float* __restrict__ as,
                                              const float* __restrict__ ad,
                                              const int* __restrict__ rowp,
                                              const int* __restrict__ col,
                                              const float* __restrict__ b2,
                                              float* __restrict__ out) {
    int n = blockIdx.x;
    int tid = threadIdx.x;
    __shared__ float sh_inv;
    int r0 = rowp[n], r1 = rowp[n + 1];
    float adn = ad[n];
    if (tid < 64) {
        float den = 0.f;
        for (int e = r0 + tid; e < r1; e += 64) {
            int s = col[e];
            float v = as[s] + adn;
            v = (v > 0.f) ? v : NEG_SLOPE * v;
            den += __expf(v);
        }
        for (int off = 32; off > 0; off >>= 1) den += __shfl_down(den, off);
        if (tid == 0) sh_inv = 1.f / (den + 1e-16f);
    }
    __syncthreads();
    float inv = sh_inv;
    float acc = 0.f;
    for (int e = r0; e < r1; e++) {
        int s = col[e];
        float v = as[s] + adn;
        v = (v > 0.f) ? v : NEG_SLOPE * v;
        float wv = __expf(v) * inv;
        acc += wv * h2[(size_t)s * OUT_CH + tid];
    }
    float v = acc + b2[tid];
    out[(size_t)n * OUT_CH + tid] = (v > 0.f) ? v : 0.f;
}

extern "C" void kernel_launch(void* const* d_in, const int* in_sizes, int n_in,
                              void* d_out, int out_size, void* d_ws, size_t ws_size,
                              hipStream_t stream) {
    const float* x      = (const float*)d_in[0];
    const int*   ei     = (const int*)d_in[1];
    const float* W1     = (const float*)d_in[2];
    const float* a_src1 = (const float*)d_in[3];
    const float* a_dst1 = (const float*)d_in[4];
    const float* b1     = (const float*)d_in[5];
    const float* W2     = (const float*)d_in[6];
    const float* a_src2 = (const float*)d_in[7];
    const float* a_dst2 = (const float*)d_in[8];
    const float* b2     = (const float*)d_in[9];
    float* out = (float*)d_out;

    // workspace layout (floats). wbuf (edge weights, ET*36) is dead after agg1,
    // so h2/as2/ad2 (2.6M floats) reuse its space (6.48M floats).
    float* ws = (float*)d_ws;
    float* h1   = ws;                                   // 25,920,000
    float* out1 = h1 + (size_t)N_NODES * HID;           // 25,920,000
    float* as1  = out1 + (size_t)N_NODES * HID;         // 720,000
    float* ad1  = as1 + (size_t)N_NODES * HEADS;        // 720,000
    float* wbuf = ad1 + (size_t)N_NODES * HEADS;        // 6,480,000 (ET*HEADS)
    float* h2   = wbuf;                                 // reuse (2,560,000)
    float* as2  = wbuf + (size_t)N_NODES * OUT_CH;      // 20,000
    float* ad2  = as2 + N_NODES;                        // 20,000
    int* cnt    = (int*)(wbuf + (size_t)ET * HEADS);    // 20,000
    int* cursor = cnt + N_NODES;                        // 20,000
    int* rowp   = cursor + N_NODES;                     // 20,001
    int* colx   = rowp + (N_NODES + 1);                 // 180,000
    int* dstn   = colx + ET;                            // 180,000

    hipMemsetAsync(cnt, 0, (size_t)2 * N_NODES * sizeof(int), stream);

    k_gemm1<<<dim3(313, 21), 256, 0, stream>>>(x, W1, h1);
    k_alpha1<<<(N_NODES * HEADS + 255) / 256, 256, 0, stream>>>(h1, a_src1, a_dst1, as1, ad1);
    k_count<<<(ET + 255) / 256, 256, 0, stream>>>(ei, cnt);
    k_scan<<<1, 1024, 0, stream>>>(cnt, rowp);
    k_fill<<<(ET + 255) / 256, 256, 0, stream>>>(ei, rowp, cursor, colx, dstn);
    k_w1<<<(ET * HEADS + 255) / 256, 256, 0, stream>>>(as1, ad1, colx, dstn, wbuf);
    k_agg1<<<N_NODES, 256, 0, stream>>>(h1, wbuf, rowp, colx, b1, out1);
    k_gemm2<<<dim3(313, 2), 256, 0, stream>>>(out1, W2, h2);
    k_alpha2<<<N_NODES, 64, 0, stream>>>(h2, a_src2, a_dst2, as2, ad2);
    k_agg2<<<N_NODES, 128, 0, stream>>>(h2, as2, ad2, rowp, colx, b2, out);
}

// Round 3
// 482.081 us; speedup vs baseline: 1.7808x; 1.1437x over previous
//
#include <hip/hip_runtime.h>

#define N_NODES 20000
#define E_EDGES 160000
#define ET (E_EDGES + N_NODES)   // 180000 with self-loops
#define IN_CH 128
#define HID 1296
#define HEADS 36
#define CPH 36
#define OUT_CH 128
#define NEG_SLOPE 0.2f

__device__ __forceinline__ float bf2f(unsigned short u) {
    union { unsigned int i; float f; } c; c.i = ((unsigned int)u) << 16; return c.f;
}
__device__ __forceinline__ unsigned short f2bf(float f) {
    union { float f; unsigned int i; } c; c.f = f;
    unsigned int r = c.i + 0x7FFF + ((c.i >> 16) & 1);   // round-to-nearest-even
    return (unsigned short)(r >> 16);
}

// ---------------- GEMM1: h1b[N,1296](bf16) = x[N,128] @ W1[128,1296] ----------------
__global__ __launch_bounds__(256) void k_gemm1(const float* __restrict__ x,
                                               const float* __restrict__ W1,
                                               unsigned short* __restrict__ h1b) {
    __shared__ float As[32][65];   // pad 65: transpose-write bank = (k4+r)%32 -> 2-way (free)
    __shared__ float Bs[32][64];
    int tid = threadIdx.x;
    int r0 = blockIdx.x * 64;
    int c0 = blockIdx.y * 64;
    int ty = tid >> 4, tx = tid & 15;
    float acc[4][4];
#pragma unroll
    for (int i = 0; i < 4; i++)
#pragma unroll
        for (int j = 0; j < 4; j++) acc[i][j] = 0.f;

    for (int k0 = 0; k0 < IN_CH; k0 += 32) {
        __syncthreads();
        {
            int k4 = (tid & 7) * 4;
#pragma unroll
            for (int i = 0; i < 2; i++) {
                int r = (tid >> 3) + i * 32;
                int gr = min(r0 + r, N_NODES - 1);
                const float4 v = *(const float4*)(x + (size_t)gr * IN_CH + k0 + k4);
                As[k4 + 0][r] = v.x; As[k4 + 1][r] = v.y;
                As[k4 + 2][r] = v.z; As[k4 + 3][r] = v.w;
            }
        }
        {
            int c4 = (tid & 15) * 4;
            int gc = min(c0 + c4, HID - 4);
#pragma unroll
            for (int i = 0; i < 2; i++) {
                int kk = (tid >> 4) + i * 16;
                *(float4*)&Bs[kk][c4] = *(const float4*)(W1 + (size_t)(k0 + kk) * HID + gc);
            }
        }
        __syncthreads();
#pragma unroll
        for (int k = 0; k < 32; k++) {
            float4 a = *(const float4*)&As[k][ty * 4];
            float4 b = *(const float4*)&Bs[k][tx * 4];
            float av[4] = {a.x, a.y, a.z, a.w};
            float bv[4] = {b.x, b.y, b.z, b.w};
#pragma unroll
            for (int i = 0; i < 4; i++)
#pragma unroll
                for (int j = 0; j < 4; j++) acc[i][j] += av[i] * bv[j];
        }
    }
#pragma unroll
    for (int i = 0; i < 4; i++) {
        int row = r0 + ty * 4 + i;
        int colc = c0 + tx * 4;
        if (row < N_NODES && colc + 3 < HID) {
            ushort4 o;
            o.x = f2bf(acc[i][0]); o.y = f2bf(acc[i][1]);
            o.z = f2bf(acc[i][2]); o.w = f2bf(acc[i][3]);
            *(ushort4*)(h1b + (size_t)row * HID + colc) = o;
        }
    }
}

// ---------------- GEMM2: h2[N,128] = out1[N,1296] @ W2[1296,128] ----------------
__global__ __launch_bounds__(256) void k_gemm2(const float* __restrict__ A,
                                               const float* __restrict__ W2,
                                               float* __restrict__ h2) {
    __shared__ float As[32][65];
    __shared__ float Bs[32][64];
    int tid = threadIdx.x;
    int r0 = blockIdx.x * 64;
    int c0 = blockIdx.y * 64;
    int ty = tid >> 4, tx = tid & 15;
    float acc[4][4];
#pragma unroll
    for (int i = 0; i < 4; i++)
#pragma unroll
        for (int j = 0; j < 4; j++) acc[i][j] = 0.f;

    for (int k0 = 0; k0 < HID; k0 += 32) {   // 41 chunks, last is 16 wide (zero-filled)
        __syncthreads();
        {
            int k4 = (tid & 7) * 4;
#pragma unroll
            for (int i = 0; i < 2; i++) {
                int r = (tid >> 3) + i * 32;
                int gr = min(r0 + r, N_NODES - 1);
                float4 v = {0.f, 0.f, 0.f, 0.f};
                if (k0 + k4 + 3 < HID) v = *(const float4*)(A + (size_t)gr * HID + k0 + k4);
                As[k4 + 0][r] = v.x; As[k4 + 1][r] = v.y;
                As[k4 + 2][r] = v.z; As[k4 + 3][r] = v.w;
            }
        }
        {
            int c4 = (tid & 15) * 4;
#pragma unroll
            for (int i = 0; i < 2; i++) {
                int kk = (tid >> 4) + i * 16;
                float4 v = {0.f, 0.f, 0.f, 0.f};
                if (k0 + kk < HID) v = *(const float4*)(W2 + (size_t)(k0 + kk) * OUT_CH + c0 + c4);
                *(float4*)&Bs[kk][c4] = v;
            }
        }
        __syncthreads();
#pragma unroll
        for (int k = 0; k < 32; k++) {
            float4 a = *(const float4*)&As[k][ty * 4];
            float4 b = *(const float4*)&Bs[k][tx * 4];
            float av[4] = {a.x, a.y, a.z, a.w};
            float bv[4] = {b.x, b.y, b.z, b.w};
#pragma unroll
            for (int i = 0; i < 4; i++)
#pragma unroll
                for (int j = 0; j < 4; j++) acc[i][j] += av[i] * bv[j];
        }
    }
#pragma unroll
    for (int i = 0; i < 4; i++) {
        int row = r0 + ty * 4 + i;
        if (row < N_NODES) {
            float4 o = {acc[i][0], acc[i][1], acc[i][2], acc[i][3]};
            *(float4*)(h2 + (size_t)row * OUT_CH + c0 + tx * 4) = o;
        }
    }
}

// ---------------- alpha1: per (node,head) dot over 36 channels (bf16 input) ----------------
__global__ __launch_bounds__(256) void k_alpha1(const unsigned short* __restrict__ h1b,
                                                const float* __restrict__ a_src,
                                                const float* __restrict__ a_dst,
                                                float* __restrict__ as,
                                                float* __restrict__ ad) {
    __shared__ float s_a[HEADS * CPH], s_b[HEADS * CPH];
    int tid = threadIdx.x;
    for (int i = tid; i < HEADS * CPH; i += 256) { s_a[i] = a_src[i]; s_b[i] = a_dst[i]; }
    __syncthreads();
    int gid = blockIdx.x * 256 + tid;
    if (gid >= N_NODES * HEADS) return;
    int n = gid / HEADS, h = gid - n * HEADS;
    const unsigned short* row = h1b + (size_t)n * HID + h * CPH;
    float ss = 0.f, sd = 0.f;
#pragma unroll
    for (int c = 0; c < CPH; c += 2) {
        uint u = *(const uint*)(row + c);        // 4B aligned: h*36+c even -> 2B*even = 4B ok
        float v0 = bf2f((unsigned short)(u & 0xFFFF));
        float v1 = bf2f((unsigned short)(u >> 16));
        ss += v0 * s_a[h * CPH + c] + v1 * s_a[h * CPH + c + 1];
        sd += v0 * s_b[h * CPH + c] + v1 * s_b[h * CPH + c + 1];
    }
    as[gid] = ss;
    ad[gid] = sd;
}

// ---------------- CSR build ----------------
__global__ void k_count(const int* __restrict__ ei, int* __restrict__ cnt) {
    int e = blockIdx.x * 256 + threadIdx.x;
    if (e >= ET) return;
    int d = (e < E_EDGES) ? ei[E_EDGES + e] : (e - E_EDGES);
    atomicAdd(&cnt[d], 1);
}

__global__ __launch_bounds__(1024) void k_scan(const int* __restrict__ cnt, int* __restrict__ rowp) {
    __shared__ int sh[1024];
    const int PER = 20;  // 1024*20 = 20480 >= 20000
    int t = threadIdx.x;
    int base = t * PER;
    int local[PER];
    int sum = 0;
    for (int i = 0; i < PER; i++) {
        int idx = base + i;
        int v = (idx < N_NODES) ? cnt[idx] : 0;
        local[i] = sum;
        sum += v;
    }
    sh[t] = sum;
    __syncthreads();
    for (int off = 1; off < 1024; off <<= 1) {
        int v = (t >= off) ? sh[t - off] : 0;
        __syncthreads();
        sh[t] += v;
        __syncthreads();
    }
    int offset = (t == 0) ? 0 : sh[t - 1];
    for (int i = 0; i < PER; i++) {
        int idx = base + i;
        if (idx < N_NODES) rowp[idx] = offset + local[i];
    }
    if (t == 1023) rowp[N_NODES] = sh[1023];
}

__global__ void k_fill(const int* __restrict__ ei, const int* __restrict__ rowp,
                       int* __restrict__ cursor, int* __restrict__ col,
                       int* __restrict__ dstn) {
    int e = blockIdx.x * 256 + threadIdx.x;
    if (e >= ET) return;
    int s, d;
    if (e < E_EDGES) { s = ei[e]; d = ei[E_EDGES + e]; }
    else { s = e - E_EDGES; d = s; }
    int pos = rowp[d] + atomicAdd(&cursor[d], 1);
    col[pos] = s;
    dstn[pos] = d;
}

// ---------------- w1: unnormalized softmax numerators per CSR position ----------------
__global__ __launch_bounds__(256) void k_w1(const float* __restrict__ as1,
                                            const float* __restrict__ ad1,
                                            const int* __restrict__ col,
                                            const int* __restrict__ dstn,
                                            float* __restrict__ w) {
    int gid = blockIdx.x * 256 + threadIdx.x;
    if (gid >= ET * HEADS) return;
    int p = gid / HEADS, h = gid - p * HEADS;
    int s = col[p], d = dstn[p];
    float v = as1[(size_t)s * HEADS + h] + ad1[(size_t)d * HEADS + h];
    v = (v > 0.f) ? v : NEG_SLOPE * v;
    w[gid] = __expf(v);
}

// ---------------- agg1: per dst node, normalize + weighted bf16x4 gather ----------------
// 1296 ch = 324 ushort4 slots; slot s covers channels 4s..4s+3, all in head s/9.
__global__ __launch_bounds__(256) void k_agg1(const unsigned short* __restrict__ h1b,
                                              const float* __restrict__ w,
                                              const int* __restrict__ rowp,
                                              const int* __restrict__ col,
                                              const float* __restrict__ b1,
                                              float* __restrict__ out1) {
    int n = blockIdx.x;
    int tid = threadIdx.x;
    int r0 = rowp[n], r1 = rowp[n + 1];
    __shared__ float inv[HEADS];
    __shared__ float wsh[32 * HEADS];
    __shared__ int   csh[32];
    if (tid < HEADS) {
        float den = 0.f;
        for (int p = r0; p < r1; p++) den += w[(size_t)p * HEADS + tid];
        inv[tid] = 1.f / (den + 1e-16f);
    }
    __syncthreads();
    float4 acc0 = {0.f, 0.f, 0.f, 0.f}, acc1 = {0.f, 0.f, 0.f, 0.f};
    int s1 = tid;              // slot 0..255
    int s2 = tid + 256;        // slot 256..323 (only tid<68)
    int h1i = s1 / 9;
    int h2i = (s2 < 324) ? s2 / 9 : 0;
    for (int p0 = r0; p0 < r1; p0 += 32) {
        int ne = min(32, r1 - p0);
        __syncthreads();
        for (int i = tid; i < ne * HEADS; i += 256) {
            int h = i % HEADS;
            wsh[i] = w[(size_t)p0 * HEADS + i] * inv[h];
        }
        if (tid < ne) csh[tid] = col[p0 + tid];
        __syncthreads();
        for (int e = 0; e < ne; e++) {
            const ushort4* hr = (const ushort4*)(h1b + (size_t)csh[e] * HID);
            float wa = wsh[e * HEADS + h1i];
            ushort4 v1 = hr[s1];
            acc0.x += wa * bf2f(v1.x); acc0.y += wa * bf2f(v1.y);
            acc0.z += wa * bf2f(v1.z); acc0.w += wa * bf2f(v1.w);
            if (s2 < 324) {
                float wb = wsh[e * HEADS + h2i];
                ushort4 v2 = hr[s2];
                acc1.x += wb * bf2f(v2.x); acc1.y += wb * bf2f(v2.y);
                acc1.z += wb * bf2f(v2.z); acc1.w += wb * bf2f(v2.w);
            }
        }
    }
    const float4* b4 = (const float4*)b1;
    float4* o4 = (float4*)(out1 + (size_t)n * HID);
    {
        float4 bb = b4[s1];
        float4 o;
        o.x = fmaxf(acc0.x + bb.x, 0.f); o.y = fmaxf(acc0.y + bb.y, 0.f);
        o.z = fmaxf(acc0.z + bb.z, 0.f); o.w = fmaxf(acc0.w + bb.w, 0.f);
        o4[s1] = o;
    }
    if (s2 < 324) {
        float4 bb = b4[s2];
        float4 o;
        o.x = fmaxf(acc1.x + bb.x, 0.f); o.y = fmaxf(acc1.y + bb.y, 0.f);
        o.z = fmaxf(acc1.z + bb.z, 0.f); o.w = fmaxf(acc1.w + bb.w, 0.f);
        o4[s2] = o;
    }
}

// ---------------- alpha2: per node dot over 128 channels (1 head) ----------------
__global__ __launch_bounds__(64) void k_alpha2(const float* __restrict__ h2,
                                               const float* __restrict__ a_src,
                                               const float* __restrict__ a_dst,
                                               float* __restrict__ as,
                                               float* __restrict__ ad) {
    int n = blockIdx.x;
    int t = threadIdx.x;
    const float* row = h2 + (size_t)n * OUT_CH;
    float v0 = row[t], v1 = row[t + 64];
    float ss = v0 * a_src[t] + v1 * a_src[t + 64];
    float sd = v0 * a_dst[t] + v1 * a_dst[t + 64];
    for (int off = 32; off > 0; off >>= 1) {
        ss += __shfl_down(ss, off);
        sd += __shfl_down(sd, off);
    }
    if (t == 0) { as[n] = ss; ad[n] = sd; }
}

// ---------------- agg2: per dst node, 1 head, C=128 ----------------
__global__ __launch_bounds__(128) void k_agg2(const float* __restrict__ h2,
                                              const float* __restrict__ as,
                                              const float* __restrict__ ad,
                                              const int* __restrict__ rowp,
                                              const int* __restrict__ col,
                                              const float* __restrict__ b2,
                                              float* __restrict__ out) {
    int n = blockIdx.x;
    int tid = threadIdx.x;
    __shared__ float sh_inv;
    int r0 = rowp[n], r1 = rowp[n + 1];
    float adn = ad[n];
    if (tid < 64) {
        float den = 0.f;
        for (int e = r0 + tid; e < r1; e += 64) {
            int s = col[e];
            float v = as[s] + adn;
            v = (v > 0.f) ? v : NEG_SLOPE * v;
            den += __expf(v);
        }
        for (int off = 32; off > 0; off >>= 1) den += __shfl_down(den, off);
        if (tid == 0) sh_inv = 1.f / (den + 1e-16f);
    }
    __syncthreads();
    float inv = sh_inv;
    float acc = 0.f;
    for (int e = r0; e < r1; e++) {
        int s = col[e];
        float v = as[s] + adn;
        v = (v > 0.f) ? v : NEG_SLOPE * v;
        float wv = __expf(v) * inv;
        acc += wv * h2[(size_t)s * OUT_CH + tid];
    }
    float v = acc + b2[tid];
    out[(size_t)n * OUT_CH + tid] = (v > 0.f) ? v : 0.f;
}

extern "C" void kernel_launch(void* const* d_in, const int* in_sizes, int n_in,
                              void* d_out, int out_size, void* d_ws, size_t ws_size,
                              hipStream_t stream) {
    const float* x      = (const float*)d_in[0];
    const int*   ei     = (const int*)d_in[1];
    const float* W1     = (const float*)d_in[2];
    const float* a_src1 = (const float*)d_in[3];
    const float* a_dst1 = (const float*)d_in[4];
    const float* b1     = (const float*)d_in[5];
    const float* W2     = (const float*)d_in[6];
    const float* a_src2 = (const float*)d_in[7];
    const float* a_dst2 = (const float*)d_in[8];
    const float* b2     = (const float*)d_in[9];
    float* out = (float*)d_out;

    // workspace layout
    float* ws = (float*)d_ws;
    unsigned short* h1b = (unsigned short*)ws;                    // 25,920,000 bf16 (51.84 MB)
    float* out1 = (float*)(h1b + (size_t)N_NODES * HID);          // 25,920,000 f32
    float* as1  = out1 + (size_t)N_NODES * HID;                   // 720,000
    float* ad1  = as1 + (size_t)N_NODES * HEADS;                  // 720,000
    float* wbuf = ad1 + (size_t)N_NODES * HEADS;                  // 6,480,000 (ET*HEADS)
    float* h2   = wbuf;                                           // reuse (2,560,000) after agg1
    float* as2  = wbuf + (size_t)N_NODES * OUT_CH;                // 20,000
    float* ad2  = as2 + N_NODES;                                  // 20,000
    int* cnt    = (int*)(wbuf + (size_t)ET * HEADS);              // 20,000
    int* cursor = cnt + N_NODES;                                  // 20,000
    int* rowp   = cursor + N_NODES;                               // 20,001
    int* colx   = rowp + (N_NODES + 1);                           // 180,000
    int* dstn   = colx + ET;                                      // 180,000

    hipMemsetAsync(cnt, 0, (size_t)2 * N_NODES * sizeof(int), stream);

    k_gemm1<<<dim3(313, 21), 256, 0, stream>>>(x, W1, h1b);
    k_alpha1<<<(N_NODES * HEADS + 255) / 256, 256, 0, stream>>>(h1b, a_src1, a_dst1, as1, ad1);
    k_count<<<(ET + 255) / 256, 256, 0, stream>>>(ei, cnt);
    k_scan<<<1, 1024, 0, stream>>>(cnt, rowp);
    k_fill<<<(ET + 255) / 256, 256, 0, stream>>>(ei, rowp, cursor, colx, dstn);
    k_w1<<<(ET * HEADS + 255) / 256, 256, 0, stream>>>(as1, ad1, colx, dstn, wbuf);
    k_agg1<<<N_NODES, 256, 0, stream>>>(h1b, wbuf, rowp, colx, b1, out1);
    k_gemm2<<<dim3(313, 2), 256, 0, stream>>>(out1, W2, h2);
    k_alpha2<<<N_NODES, 64, 0, stream>>>(h2, a_src2, a_dst2, as2, ad2);
    k_agg2<<<N_NODES, 128, 0, stream>>>(h2, as2, ad2, rowp, colx, b2, out);
}

// Round 4
// 332.008 us; speedup vs baseline: 2.5857x; 1.4520x over previous
//
#include <hip/hip_runtime.h>

#define N_NODES 20000
#define E_EDGES 160000
#define ET (E_EDGES + N_NODES)   // 180000 with self-loops
#define IN_CH 128
#define HID 1296
#define HEADS 36
#define CPH 36
#define OUT_CH 128
#define KP2 1344                 // HID padded to 21*64 for gemm2 K-loop
#define NEG_SLOPE 0.2f

typedef __attribute__((ext_vector_type(8))) short bf16x8;
typedef __attribute__((ext_vector_type(4))) float floatx4;

__device__ __forceinline__ float bf2f(unsigned short u) {
    union { unsigned int i; float f; } c; c.i = ((unsigned int)u) << 16; return c.f;
}
__device__ __forceinline__ unsigned short f2bf(float f) {
    union { float f; unsigned int i; } c; c.f = f;
    unsigned int r = c.i + 0x7FFF + ((c.i >> 16) & 1);   // round-to-nearest-even
    return (unsigned short)(r >> 16);
}

// ---------------- prep: cast x to bf16 ----------------
__global__ __launch_bounds__(256) void k_castx(const float* __restrict__ x,
                                               unsigned short* __restrict__ xb) {
    int i = blockIdx.x * 256 + threadIdx.x;          // one float4 -> ushort4
    if (i >= N_NODES * IN_CH / 4) return;
    float4 v = ((const float4*)x)[i];
    ushort4 o; o.x = f2bf(v.x); o.y = f2bf(v.y); o.z = f2bf(v.z); o.w = f2bf(v.w);
    ((ushort4*)xb)[i] = o;
}

// ---------------- prep: W1[128,1296] f32 -> W1T[1296,128] bf16 ----------------
__global__ __launch_bounds__(256) void k_w1t(const float* __restrict__ W1,
                                             unsigned short* __restrict__ W1T) {
    int gid = blockIdx.x * 256 + threadIdx.x;
    if (gid >= HID * IN_CH) return;
    int n = gid >> 7, k = gid & 127;
    W1T[gid] = f2bf(W1[(size_t)k * HID + n]);
}

// ---------------- prep: W2[1296,128] f32 -> W2T[128,1344] bf16 (zero pad) ----------------
__global__ __launch_bounds__(256) void k_w2t(const float* __restrict__ W2,
                                             unsigned short* __restrict__ W2T) {
    int gid = blockIdx.x * 256 + threadIdx.x;
    if (gid >= OUT_CH * KP2) return;
    int n = gid / KP2, k = gid - n * KP2;
    W2T[gid] = (k < HID) ? f2bf(W2[(size_t)k * OUT_CH + n]) : 0;
}

// ---------------- GEMM1 (MFMA): h1b[N,1296] = xb[N,128] @ W1T^T ----------------
// block tile 128x64, 4 waves, wave tile 32x64 (2x4 of 16x16x32). Whole K=128 in LDS.
__global__ __launch_bounds__(256) void k_gemm1(const unsigned short* __restrict__ xb,
                                               const unsigned short* __restrict__ W1T,
                                               unsigned short* __restrict__ h1b) {
    __shared__ unsigned short As[128][136];   // [m][k], stride 136 -> uniform bank groups
    __shared__ unsigned short Bs[64][136];    // [n][k]
    int tid = threadIdx.x;
    int r0 = blockIdx.x * 128;
    int n0 = blockIdx.y * 64;
    // stage A: 128 rows x 16 chunks(16B)
#pragma unroll
    for (int i = 0; i < 8; i++) {
        int c = tid + i * 256;
        int row = c >> 4, kc = (c & 15) * 8;
        int gr = min(r0 + row, N_NODES - 1);
        *(bf16x8*)&As[row][kc] = *(const bf16x8*)(xb + (size_t)gr * IN_CH + kc);
    }
    // stage B: 64 rows x 16 chunks
#pragma unroll
    for (int i = 0; i < 4; i++) {
        int c = tid + i * 256;
        int row = c >> 4, kc = (c & 15) * 8;
        int gn = min(n0 + row, HID - 1);
        *(bf16x8*)&Bs[row][kc] = *(const bf16x8*)(W1T + (size_t)gn * IN_CH + kc);
    }
    __syncthreads();
    int lane = tid & 63, w = tid >> 6;
    int quad = lane >> 4, l15 = lane & 15;
    int mbase = w * 32;
    floatx4 acc[2][4];
#pragma unroll
    for (int i = 0; i < 2; i++)
#pragma unroll
        for (int j = 0; j < 4; j++) acc[i][j] = (floatx4){0.f, 0.f, 0.f, 0.f};
#pragma unroll
    for (int kc = 0; kc < 128; kc += 32) {
        bf16x8 a0 = *(const bf16x8*)&As[mbase + l15][kc + quad * 8];
        bf16x8 a1 = *(const bf16x8*)&As[mbase + 16 + l15][kc + quad * 8];
#pragma unroll
        for (int j = 0; j < 4; j++) {
            bf16x8 b = *(const bf16x8*)&Bs[j * 16 + l15][kc + quad * 8];
            acc[0][j] = __builtin_amdgcn_mfma_f32_16x16x32_bf16(a0, b, acc[0][j], 0, 0, 0);
            acc[1][j] = __builtin_amdgcn_mfma_f32_16x16x32_bf16(a1, b, acc[1][j], 0, 0, 0);
        }
    }
#pragma unroll
    for (int i = 0; i < 2; i++)
#pragma unroll
        for (int j = 0; j < 4; j++) {
            int colc = n0 + j * 16 + l15;
            if (colc >= HID) continue;
#pragma unroll
            for (int r = 0; r < 4; r++) {
                int row = r0 + mbase + i * 16 + quad * 4 + r;
                if (row < N_NODES)
                    h1b[(size_t)row * HID + colc] = f2bf(acc[i][j][r]);
            }
        }
}

// ---------------- GEMM2 (MFMA, split-K x2): h2{a,b}[N,128] = out1b @ W2T^T ----------------
// block tile 64x128, 4 waves, wave tile 32x64. BK=32, 21 iters over K-half 672.
__global__ __launch_bounds__(256) void k_gemm2(const unsigned short* __restrict__ A,
                                               const unsigned short* __restrict__ W2T,
                                               float* __restrict__ h2a,
                                               float* __restrict__ h2b) {
    __shared__ unsigned short As[64][40];
    __shared__ unsigned short Bs[128][40];
    int tid = threadIdx.x;
    int r0 = blockIdx.x * 64;
    int kbase = blockIdx.y * 672;
    int lane = tid & 63, w = tid >> 6;
    int quad = lane >> 4, l15 = lane & 15;
    int mbase = (w & 1) * 32;
    int nbase = (w >> 1) * 64;
    floatx4 acc[2][4];
#pragma unroll
    for (int i = 0; i < 2; i++)
#pragma unroll
        for (int j = 0; j < 4; j++) acc[i][j] = (floatx4){0.f, 0.f, 0.f, 0.f};

    for (int it = 0; it < 21; it++) {
        int k0 = kbase + it * 32;
        __syncthreads();
        {   // stage A: 64 rows x 4 chunks
            int row = tid >> 2, kc = (tid & 3) * 8;
            int gr = min(r0 + row, N_NODES - 1);
            *(bf16x8*)&As[row][kc] = *(const bf16x8*)(A + (size_t)gr * KP2 + k0 + kc);
        }
        {   // stage B: 128 rows x 4 chunks
#pragma unroll
            for (int i = 0; i < 2; i++) {
                int c = tid + i * 256;
                int row = c >> 2, kc = (c & 3) * 8;
                *(bf16x8*)&Bs[row][kc] = *(const bf16x8*)(W2T + (size_t)row * KP2 + k0 + kc);
            }
        }
        __syncthreads();
        bf16x8 a0 = *(const bf16x8*)&As[mbase + l15][quad * 8];
        bf16x8 a1 = *(const bf16x8*)&As[mbase + 16 + l15][quad * 8];
#pragma unroll
        for (int j = 0; j < 4; j++) {
            bf16x8 b = *(const bf16x8*)&Bs[nbase + j * 16 + l15][quad * 8];
            acc[0][j] = __builtin_amdgcn_mfma_f32_16x16x32_bf16(a0, b, acc[0][j], 0, 0, 0);
            acc[1][j] = __builtin_amdgcn_mfma_f32_16x16x32_bf16(a1, b, acc[1][j], 0, 0, 0);
        }
    }
    float* dst = (blockIdx.y == 0) ? h2a : h2b;
#pragma unroll
    for (int i = 0; i < 2; i++)
#pragma unroll
        for (int j = 0; j < 4; j++) {
            int colc = nbase + j * 16 + l15;
#pragma unroll
            for (int r = 0; r < 4; r++) {
                int row = r0 + mbase + i * 16 + quad * 4 + r;
                if (row < N_NODES)
                    dst[(size_t)row * OUT_CH + colc] = acc[i][j][r];
            }
        }
}

// ---------------- alpha1: per (node,head) dot over 36 channels (bf16 input) ----------------
__global__ __launch_bounds__(256) void k_alpha1(const unsigned short* __restrict__ h1b,
                                                const float* __restrict__ a_src,
                                                const float* __restrict__ a_dst,
                                                float* __restrict__ as,
                                                float* __restrict__ ad) {
    __shared__ float s_a[HEADS * CPH], s_b[HEADS * CPH];
    int tid = threadIdx.x;
    for (int i = tid; i < HEADS * CPH; i += 256) { s_a[i] = a_src[i]; s_b[i] = a_dst[i]; }
    __syncthreads();
    int gid = blockIdx.x * 256 + tid;
    if (gid >= N_NODES * HEADS) return;
    int n = gid / HEADS, h = gid - n * HEADS;
    const unsigned short* row = h1b + (size_t)n * HID + h * CPH;
    float ss = 0.f, sd = 0.f;
#pragma unroll
    for (int c = 0; c < CPH; c += 2) {
        uint u = *(const uint*)(row + c);
        float v0 = bf2f((unsigned short)(u & 0xFFFF));
        float v1 = bf2f((unsigned short)(u >> 16));
        ss += v0 * s_a[h * CPH + c] + v1 * s_a[h * CPH + c + 1];
        sd += v0 * s_b[h * CPH + c] + v1 * s_b[h * CPH + c + 1];
    }
    as[gid] = ss;
    ad[gid] = sd;
}

// ---------------- CSR build ----------------
__global__ void k_count(const int* __restrict__ ei, int* __restrict__ cnt) {
    int e = blockIdx.x * 256 + threadIdx.x;
    if (e >= ET) return;
    int d = (e < E_EDGES) ? ei[E_EDGES + e] : (e - E_EDGES);
    atomicAdd(&cnt[d], 1);
}

__global__ __launch_bounds__(1024) void k_scan(const int* __restrict__ cnt, int* __restrict__ rowp) {
    __shared__ int sh[1024];
    const int PER = 20;
    int t = threadIdx.x;
    int base = t * PER;
    int local[PER];
    int sum = 0;
    for (int i = 0; i < PER; i++) {
        int idx = base + i;
        int v = (idx < N_NODES) ? cnt[idx] : 0;
        local[i] = sum;
        sum += v;
    }
    sh[t] = sum;
    __syncthreads();
    for (int off = 1; off < 1024; off <<= 1) {
        int v = (t >= off) ? sh[t - off] : 0;
        __syncthreads();
        sh[t] += v;
        __syncthreads();
    }
    int offset = (t == 0) ? 0 : sh[t - 1];
    for (int i = 0; i < PER; i++) {
        int idx = base + i;
        if (idx < N_NODES) rowp[idx] = offset + local[i];
    }
    if (t == 1023) rowp[N_NODES] = sh[1023];
}

__global__ void k_fill(const int* __restrict__ ei, const int* __restrict__ rowp,
                       int* __restrict__ cursor, int* __restrict__ col,
                       int* __restrict__ dstn) {
    int e = blockIdx.x * 256 + threadIdx.x;
    if (e >= ET) return;
    int s, d;
    if (e < E_EDGES) { s = ei[e]; d = ei[E_EDGES + e]; }
    else { s = e - E_EDGES; d = s; }
    int pos = rowp[d] + atomicAdd(&cursor[d], 1);
    col[pos] = s;
    dstn[pos] = d;
}

// ---------------- w1: unnormalized softmax numerators per CSR position ----------------
__global__ __launch_bounds__(256) void k_w1(const float* __restrict__ as1,
                                            const float* __restrict__ ad1,
                                            const int* __restrict__ col,
                                            const int* __restrict__ dstn,
                                            float* __restrict__ w) {
    int gid = blockIdx.x * 256 + threadIdx.x;
    if (gid >= ET * HEADS) return;
    int p = gid / HEADS, h = gid - p * HEADS;
    int s = col[p], d = dstn[p];
    float v = as1[(size_t)s * HEADS + h] + ad1[(size_t)d * HEADS + h];
    v = (v > 0.f) ? v : NEG_SLOPE * v;
    w[gid] = __expf(v);
}

// ---------------- agg1: per dst node, normalize + weighted bf16x4 gather ----------------
// writes out1b bf16 [N][KP2], relu(acc+bias), zero pad cols [1296,1344)
__global__ __launch_bounds__(256) void k_agg1(const unsigned short* __restrict__ h1b,
                                              const float* __restrict__ w,
                                              const int* __restrict__ rowp,
                                              const int* __restrict__ col,
                                              const float* __restrict__ b1,
                                              unsigned short* __restrict__ out1b) {
    int n = blockIdx.x;
    int tid = threadIdx.x;
    int r0 = rowp[n], r1 = rowp[n + 1];
    __shared__ float inv[HEADS];
    __shared__ float wsh[32 * HEADS];
    __shared__ int   csh[32];
    if (tid < HEADS) {
        float den = 0.f;
        for (int p = r0; p < r1; p++) den += w[(size_t)p * HEADS + tid];
        inv[tid] = 1.f / (den + 1e-16f);
    }
    __syncthreads();
    float4 acc0 = {0.f, 0.f, 0.f, 0.f}, acc1 = {0.f, 0.f, 0.f, 0.f};
    int s1 = tid;              // slot 0..255
    int s2 = tid + 256;        // slot 256..335
    int h1i = s1 / 9;
    int h2i = (s2 < 324) ? s2 / 9 : 0;
    for (int p0 = r0; p0 < r1; p0 += 32) {
        int ne = min(32, r1 - p0);
        __syncthreads();
        for (int i = tid; i < ne * HEADS; i += 256) {
            int h = i % HEADS;
            wsh[i] = w[(size_t)p0 * HEADS + i] * inv[h];
        }
        if (tid < ne) csh[tid] = col[p0 + tid];
        __syncthreads();
        for (int e = 0; e < ne; e++) {
            const ushort4* hr = (const ushort4*)(h1b + (size_t)csh[e] * HID);
            float wa = wsh[e * HEADS + h1i];
            ushort4 v1 = hr[s1];
            acc0.x += wa * bf2f(v1.x); acc0.y += wa * bf2f(v1.y);
            acc0.z += wa * bf2f(v1.z); acc0.w += wa * bf2f(v1.w);
            if (s2 < 324) {
                float wb = wsh[e * HEADS + h2i];
                ushort4 v2 = hr[s2];
                acc1.x += wb * bf2f(v2.x); acc1.y += wb * bf2f(v2.y);
                acc1.z += wb * bf2f(v2.z); acc1.w += wb * bf2f(v2.w);
            }
        }
    }
    const float4* b4 = (const float4*)b1;
    ushort4* o4 = (ushort4*)(out1b + (size_t)n * KP2);
    {
        float4 bb = b4[s1];
        ushort4 o;
        o.x = f2bf(fmaxf(acc0.x + bb.x, 0.f)); o.y = f2bf(fmaxf(acc0.y + bb.y, 0.f));
        o.z = f2bf(fmaxf(acc0.z + bb.z, 0.f)); o.w = f2bf(fmaxf(acc0.w + bb.w, 0.f));
        o4[s1] = o;
    }
    if (s2 < 324) {
        float4 bb = b4[s2];
        ushort4 o;
        o.x = f2bf(fmaxf(acc1.x + bb.x, 0.f)); o.y = f2bf(fmaxf(acc1.y + bb.y, 0.f));
        o.z = f2bf(fmaxf(acc1.z + bb.z, 0.f)); o.w = f2bf(fmaxf(acc1.w + bb.w, 0.f));
        o4[s2] = o;
    } else if (s2 < KP2 / 4) {
        o4[s2] = (ushort4){0, 0, 0, 0};   // zero K-pad for gemm2
    }
}

// ---------------- alpha2c: combine split-K halves + per-node dots ----------------
__global__ __launch_bounds__(64) void k_alpha2c(const float* __restrict__ h2a,
                                                const float* __restrict__ h2b,
                                                float* __restrict__ h2,
                                                const float* __restrict__ a_src,
                                                const float* __restrict__ a_dst,
                                                float* __restrict__ as,
                                                float* __restrict__ ad) {
    int n = blockIdx.x;
    int t = threadIdx.x;
    size_t base = (size_t)n * OUT_CH;
    float v0 = h2a[base + t] + h2b[base + t];
    float v1 = h2a[base + t + 64] + h2b[base + t + 64];
    h2[base + t] = v0;
    h2[base + t + 64] = v1;
    float ss = v0 * a_src[t] + v1 * a_src[t + 64];
    float sd = v0 * a_dst[t] + v1 * a_dst[t + 64];
    for (int off = 32; off > 0; off >>= 1) {
        ss += __shfl_down(ss, off);
        sd += __shfl_down(sd, off);
    }
    if (t == 0) { as[n] = ss; ad[n] = sd; }
}

// ---------------- agg2: per dst node, 1 head, C=128 ----------------
__global__ __launch_bounds__(128) void k_agg2(const float* __restrict__ h2,
                                              const float* __restrict__ as,
                                              const float* __restrict__ ad,
                                              const int* __restrict__ rowp,
                                              const int* __restrict__ col,
                                              const float* __restrict__ b2,
                                              float* __restrict__ out) {
    int n = blockIdx.x;
    int tid = threadIdx.x;
    __shared__ float sh_inv;
    int r0 = rowp[n], r1 = rowp[n + 1];
    float adn = ad[n];
    if (tid < 64) {
        float den = 0.f;
        for (int e = r0 + tid; e < r1; e += 64) {
            int s = col[e];
            float v = as[s] + adn;
            v = (v > 0.f) ? v : NEG_SLOPE * v;
            den += __expf(v);
        }
        for (int off = 32; off > 0; off >>= 1) den += __shfl_down(den, off);
        if (tid == 0) sh_inv = 1.f / (den + 1e-16f);
    }
    __syncthreads();
    float inv = sh_inv;
    float acc = 0.f;
    for (int e = r0; e < r1; e++) {
        int s = col[e];
        float v = as[s] + adn;
        v = (v > 0.f) ? v : NEG_SLOPE * v;
        float wv = __expf(v) * inv;
        acc += wv * h2[(size_t)s * OUT_CH + tid];
    }
    float v = acc + b2[tid];
    out[(size_t)n * OUT_CH + tid] = (v > 0.f) ? v : 0.f;
}

extern "C" void kernel_launch(void* const* d_in, const int* in_sizes, int n_in,
                              void* d_out, int out_size, void* d_ws, size_t ws_size,
                              hipStream_t stream) {
    const float* x      = (const float*)d_in[0];
    const int*   ei     = (const int*)d_in[1];
    const float* W1     = (const float*)d_in[2];
    const float* a_src1 = (const float*)d_in[3];
    const float* a_dst1 = (const float*)d_in[4];
    const float* b1     = (const float*)d_in[5];
    const float* W2     = (const float*)d_in[6];
    const float* a_src2 = (const float*)d_in[7];
    const float* a_dst2 = (const float*)d_in[8];
    const float* b2     = (const float*)d_in[9];
    float* out = (float*)d_out;

    // ---- workspace layout ----
    unsigned short* h1b   = (unsigned short*)d_ws;                 // 25,920,000
    unsigned short* out1b = h1b + (size_t)N_NODES * HID;           // 26,880,000 (N*KP2)
    unsigned short* xb    = out1b + (size_t)N_NODES * KP2;         // 2,560,000
    unsigned short* W1T   = xb + (size_t)N_NODES * IN_CH;          // 165,888
    unsigned short* W2T   = W1T + (size_t)HID * IN_CH;             // 172,032
    float* fbase = (float*)(W2T + (size_t)OUT_CH * KP2);
    float* as1  = fbase;                                           // 720,000
    float* ad1  = as1 + (size_t)N_NODES * HEADS;                   // 720,000
    float* wbuf = ad1 + (size_t)N_NODES * HEADS;                   // 6,480,000 (ET*HEADS)
    float* h2a  = wbuf;                                            // reuse after agg1 (2.56M)
    float* h2b  = wbuf + (size_t)N_NODES * OUT_CH;                 // 2.56M (fits in wbuf)
    float* h2   = wbuf + (size_t)ET * HEADS;                       // 2,560,000
    float* as2  = h2 + (size_t)N_NODES * OUT_CH;                   // 20,000
    float* ad2  = as2 + N_NODES;                                   // 20,000
    int* cnt    = (int*)(ad2 + N_NODES);                           // 20,000
    int* cursor = cnt + N_NODES;                                   // 20,000
    int* rowp   = cursor + N_NODES;                                // 20,001
    int* colx   = rowp + (N_NODES + 1);                            // 180,000
    int* dstn   = colx + ET;                                       // 180,000

    hipMemsetAsync(cnt, 0, (size_t)2 * N_NODES * sizeof(int), stream);

    k_castx<<<(N_NODES * IN_CH / 4 + 255) / 256, 256, 0, stream>>>(x, xb);
    k_w1t<<<(HID * IN_CH + 255) / 256, 256, 0, stream>>>(W1, W1T);
    k_w2t<<<(OUT_CH * KP2 + 255) / 256, 256, 0, stream>>>(W2, W2T);

    k_gemm1<<<dim3(157, 21), 256, 0, stream>>>(xb, W1T, h1b);
    k_alpha1<<<(N_NODES * HEADS + 255) / 256, 256, 0, stream>>>(h1b, a_src1, a_dst1, as1, ad1);
    k_count<<<(ET + 255) / 256, 256, 0, stream>>>(ei, cnt);
    k_scan<<<1, 1024, 0, stream>>>(cnt, rowp);
    k_fill<<<(ET + 255) / 256, 256, 0, stream>>>(ei, rowp, cursor, colx, dstn);
    k_w1<<<(ET * HEADS + 255) / 256, 256, 0, stream>>>(as1, ad1, colx, dstn, wbuf);
    k_agg1<<<N_NODES, 256, 0, stream>>>(h1b, wbuf, rowp, colx, b1, out1b);
    k_gemm2<<<dim3(313, 2), 256, 0, stream>>>(out1b, W2T, h2a, h2b);
    k_alpha2c<<<N_NODES, 64, 0, stream>>>(h2a, h2b, h2, a_src2, a_dst2, as2, ad2);
    k_agg2<<<N_NODES, 128, 0, stream>>>(h2, as2, ad2, rowp, colx, b2, out);
}

// Round 6
// 322.973 us; speedup vs baseline: 2.6580x; 1.0280x over previous
//
#include <hip/hip_runtime.h>

#define N_NODES 20000
#define E_EDGES 160000
#define ET (E_EDGES + N_NODES)   // 180000 with self-loops
#define IN_CH 128
#define HID 1296
#define HEADS 36
#define CPH 36
#define OUT_CH 128
#define KP2 1344                 // HID padded to 21*64 for gemm2 K-loop
#define NEG_SLOPE 0.2f

typedef __attribute__((ext_vector_type(8))) short bf16x8;
typedef __attribute__((ext_vector_type(4))) float floatx4;

__device__ __forceinline__ float bf2f(unsigned short u) {
    union { unsigned int i; float f; } c; c.i = ((unsigned int)u) << 16; return c.f;
}
__device__ __forceinline__ unsigned short f2bf(float f) {
    union { float f; unsigned int i; } c; c.f = f;
    unsigned int r = c.i + 0x7FFF + ((c.i >> 16) & 1);   // round-to-nearest-even
    return (unsigned short)(r >> 16);
}

// ---------------- prep (fused): cast x->bf16, W1->W1T bf16, W2->W2T bf16 ----------------
#define NX (N_NODES * IN_CH / 4)      // 640000 float4 units
#define NW1 (HID * IN_CH)             // 165888
#define NW2 (OUT_CH * KP2)            // 172032
__global__ __launch_bounds__(256) void k_prep(const float* __restrict__ x,
                                              unsigned short* __restrict__ xb,
                                              const float* __restrict__ W1,
                                              unsigned short* __restrict__ W1T,
                                              const float* __restrict__ W2,
                                              unsigned short* __restrict__ W2T) {
    int gid = blockIdx.x * 256 + threadIdx.x;
    if (gid < NX) {
        float4 v = ((const float4*)x)[gid];
        ushort4 o; o.x = f2bf(v.x); o.y = f2bf(v.y); o.z = f2bf(v.z); o.w = f2bf(v.w);
        ((ushort4*)xb)[gid] = o;
    } else if (gid < NX + NW1) {
        int g = gid - NX;
        int n = g >> 7, k = g & 127;
        W1T[g] = f2bf(W1[(size_t)k * HID + n]);
    } else if (gid < NX + NW1 + NW2) {
        int g = gid - NX - NW1;
        int n = g / KP2, k = g - n * KP2;
        W2T[g] = (k < HID) ? f2bf(W2[(size_t)k * OUT_CH + n]) : 0;
    }
}

// ---------------- GEMM1 (MFMA): h1b[N,1296] = xb[N,128] @ W1T^T ----------------
__global__ __launch_bounds__(256) void k_gemm1(const unsigned short* __restrict__ xb,
                                               const unsigned short* __restrict__ W1T,
                                               unsigned short* __restrict__ h1b) {
    __shared__ unsigned short As[128][136];
    __shared__ unsigned short Bs[64][136];
    int tid = threadIdx.x;
    int r0 = blockIdx.x * 128;
    int n0 = blockIdx.y * 64;
#pragma unroll
    for (int i = 0; i < 8; i++) {
        int c = tid + i * 256;
        int row = c >> 4, kc = (c & 15) * 8;
        int gr = min(r0 + row, N_NODES - 1);
        *(bf16x8*)&As[row][kc] = *(const bf16x8*)(xb + (size_t)gr * IN_CH + kc);
    }
#pragma unroll
    for (int i = 0; i < 4; i++) {
        int c = tid + i * 256;
        int row = c >> 4, kc = (c & 15) * 8;
        int gn = min(n0 + row, HID - 1);
        *(bf16x8*)&Bs[row][kc] = *(const bf16x8*)(W1T + (size_t)gn * IN_CH + kc);
    }
    __syncthreads();
    int lane = tid & 63, w = tid >> 6;
    int quad = lane >> 4, l15 = lane & 15;
    int mbase = w * 32;
    floatx4 acc[2][4];
#pragma unroll
    for (int i = 0; i < 2; i++)
#pragma unroll
        for (int j = 0; j < 4; j++) acc[i][j] = (floatx4){0.f, 0.f, 0.f, 0.f};
#pragma unroll
    for (int kc = 0; kc < 128; kc += 32) {
        bf16x8 a0 = *(const bf16x8*)&As[mbase + l15][kc + quad * 8];
        bf16x8 a1 = *(const bf16x8*)&As[mbase + 16 + l15][kc + quad * 8];
#pragma unroll
        for (int j = 0; j < 4; j++) {
            bf16x8 b = *(const bf16x8*)&Bs[j * 16 + l15][kc + quad * 8];
            acc[0][j] = __builtin_amdgcn_mfma_f32_16x16x32_bf16(a0, b, acc[0][j], 0, 0, 0);
            acc[1][j] = __builtin_amdgcn_mfma_f32_16x16x32_bf16(a1, b, acc[1][j], 0, 0, 0);
        }
    }
#pragma unroll
    for (int i = 0; i < 2; i++)
#pragma unroll
        for (int j = 0; j < 4; j++) {
            int colc = n0 + j * 16 + l15;
            if (colc >= HID) continue;
#pragma unroll
            for (int r = 0; r < 4; r++) {
                int row = r0 + mbase + i * 16 + quad * 4 + r;
                if (row < N_NODES)
                    h1b[(size_t)row * HID + colc] = f2bf(acc[i][j][r]);
            }
        }
}

// ---------------- GEMM2 (MFMA, split-K x2, 32-row tiles): h2{a,b}[N,128] ----------------
__global__ __launch_bounds__(256) void k_gemm2(const unsigned short* __restrict__ A,
                                               const unsigned short* __restrict__ W2T,
                                               float* __restrict__ h2a,
                                               float* __restrict__ h2b) {
    __shared__ unsigned short As[32][40];
    __shared__ unsigned short Bs[128][40];
    int tid = threadIdx.x;
    int r0 = blockIdx.x * 32;                 // 625*32 = 20000 exact
    int kbase = blockIdx.y * 672;
    int lane = tid & 63, w = tid >> 6;
    int quad = lane >> 4, l15 = lane & 15;
    int nbase = w * 32;
    floatx4 acc[2][2];
#pragma unroll
    for (int i = 0; i < 2; i++)
#pragma unroll
        for (int j = 0; j < 2; j++) acc[i][j] = (floatx4){0.f, 0.f, 0.f, 0.f};

    for (int it = 0; it < 21; it++) {
        int k0 = kbase + it * 32;
        __syncthreads();
        if (tid < 128) {
            int row = tid >> 2, kc = (tid & 3) * 8;
            *(bf16x8*)&As[row][kc] = *(const bf16x8*)(A + (size_t)(r0 + row) * KP2 + k0 + kc);
        }
#pragma unroll
        for (int i = 0; i < 2; i++) {
            int c = tid + i * 256;
            int row = c >> 2, kc = (c & 3) * 8;
            *(bf16x8*)&Bs[row][kc] = *(const bf16x8*)(W2T + (size_t)row * KP2 + k0 + kc);
        }
        __syncthreads();
        bf16x8 a0 = *(const bf16x8*)&As[l15][quad * 8];
        bf16x8 a1 = *(const bf16x8*)&As[16 + l15][quad * 8];
        bf16x8 b0 = *(const bf16x8*)&Bs[nbase + l15][quad * 8];
        bf16x8 b1 = *(const bf16x8*)&Bs[nbase + 16 + l15][quad * 8];
        acc[0][0] = __builtin_amdgcn_mfma_f32_16x16x32_bf16(a0, b0, acc[0][0], 0, 0, 0);
        acc[1][0] = __builtin_amdgcn_mfma_f32_16x16x32_bf16(a1, b0, acc[1][0], 0, 0, 0);
        acc[0][1] = __builtin_amdgcn_mfma_f32_16x16x32_bf16(a0, b1, acc[0][1], 0, 0, 0);
        acc[1][1] = __builtin_amdgcn_mfma_f32_16x16x32_bf16(a1, b1, acc[1][1], 0, 0, 0);
    }
    float* dst = (blockIdx.y == 0) ? h2a : h2b;
#pragma unroll
    for (int i = 0; i < 2; i++)
#pragma unroll
        for (int j = 0; j < 2; j++) {
            int colc = nbase + j * 16 + l15;
#pragma unroll
            for (int r = 0; r < 4; r++) {
                int row = r0 + i * 16 + quad * 4 + r;
                dst[(size_t)row * OUT_CH + colc] = acc[i][j][r];
            }
        }
}

// ---------------- alpha1: per (node,head) dot over 36 channels (bf16 input) ----------------
__global__ __launch_bounds__(256) void k_alpha1(const unsigned short* __restrict__ h1b,
                                                const float* __restrict__ a_src,
                                                const float* __restrict__ a_dst,
                                                float* __restrict__ as,
                                                float* __restrict__ ad) {
    __shared__ float s_a[HEADS * CPH], s_b[HEADS * CPH];
    int tid = threadIdx.x;
    for (int i = tid; i < HEADS * CPH; i += 256) { s_a[i] = a_src[i]; s_b[i] = a_dst[i]; }
    __syncthreads();
    int gid = blockIdx.x * 256 + tid;
    if (gid >= N_NODES * HEADS) return;
    int n = gid / HEADS, h = gid - n * HEADS;
    const unsigned short* row = h1b + (size_t)n * HID + h * CPH;
    float ss = 0.f, sd = 0.f;
#pragma unroll
    for (int c = 0; c < CPH; c += 2) {
        uint u = *(const uint*)(row + c);
        float v0 = bf2f((unsigned short)(u & 0xFFFF));
        float v1 = bf2f((unsigned short)(u >> 16));
        ss += v0 * s_a[h * CPH + c] + v1 * s_a[h * CPH + c + 1];
        sd += v0 * s_b[h * CPH + c] + v1 * s_b[h * CPH + c + 1];
    }
    as[gid] = ss;
    ad[gid] = sd;
}

// ---------------- CSR build ----------------
__global__ void k_count(const int* __restrict__ ei, int* __restrict__ cnt) {
    int e = blockIdx.x * 256 + threadIdx.x;
    if (e >= ET) return;
    int d = (e < E_EDGES) ? ei[E_EDGES + e] : (e - E_EDGES);
    atomicAdd(&cnt[d], 1);
}

__global__ __launch_bounds__(1024) void k_scan(const int* __restrict__ cnt, int* __restrict__ rowp) {
    __shared__ int sh[1024];
    const int PER = 20;
    int t = threadIdx.x;
    int base = t * PER;
    int local[PER];
    int sum = 0;
    for (int i = 0; i < PER; i++) {
        int idx = base + i;
        int v = (idx < N_NODES) ? cnt[idx] : 0;
        local[i] = sum;
        sum += v;
    }
    sh[t] = sum;
    __syncthreads();
    for (int off = 1; off < 1024; off <<= 1) {
        int v = (t >= off) ? sh[t - off] : 0;
        __syncthreads();
        sh[t] += v;
        __syncthreads();
    }
    int offset = (t == 0) ? 0 : sh[t - 1];
    for (int i = 0; i < PER; i++) {
        int idx = base + i;
        if (idx < N_NODES) rowp[idx] = offset + local[i];
    }
    if (t == 1023) rowp[N_NODES] = sh[1023];
}

__global__ void k_fill(const int* __restrict__ ei, const int* __restrict__ rowp,
                       int* __restrict__ cursor, int* __restrict__ col,
                       int* __restrict__ dstn) {
    int e = blockIdx.x * 256 + threadIdx.x;
    if (e >= ET) return;
    int s, d;
    if (e < E_EDGES) { s = ei[e]; d = ei[E_EDGES + e]; }
    else { s = e - E_EDGES; d = s; }
    int pos = rowp[d] + atomicAdd(&cursor[d], 1);
    col[pos] = s;
    dstn[pos] = d;
}

// ---------------- w1: edge weights + atomic softmax denominator ----------------
__global__ __launch_bounds__(256) void k_w1(const float* __restrict__ as1,
                                            const float* __restrict__ ad1,
                                            const int* __restrict__ col,
                                            const int* __restrict__ dstn,
                                            float* __restrict__ w,
                                            float* __restrict__ den) {
    int gid = blockIdx.x * 256 + threadIdx.x;
    if (gid >= ET * HEADS) return;
    int p = gid / HEADS, h = gid - p * HEADS;
    int s = col[p], d = dstn[p];
    float v = as1[(size_t)s * HEADS + h] + ad1[(size_t)d * HEADS + h];
    v = (v > 0.f) ? v : NEG_SLOPE * v;
    float ev = __expf(v);
    w[gid] = ev;
    atomicAdd(&den[(size_t)d * HEADS + h], ev);
}

// ---------------- agg1: weighted bf16x4 gather, 2-edge unrolled ----------------
__global__ __launch_bounds__(256) void k_agg1(const unsigned short* __restrict__ h1b,
                                              const float* __restrict__ w,
                                              const float* __restrict__ den,
                                              const int* __restrict__ rowp,
                                              const int* __restrict__ col,
                                              const float* __restrict__ b1,
                                              unsigned short* __restrict__ out1b) {
    int n = blockIdx.x;
    int tid = threadIdx.x;
    int r0 = rowp[n], r1 = rowp[n + 1];
    __shared__ float inv[HEADS];
    __shared__ float wsh[32 * HEADS];
    __shared__ int   csh[32];
    if (tid < HEADS) inv[tid] = 1.f / (den[(size_t)n * HEADS + tid] + 1e-16f);
    float4 acc0 = {0.f, 0.f, 0.f, 0.f}, acc1 = {0.f, 0.f, 0.f, 0.f};
    int s1 = tid;              // slot 0..255
    int s2 = tid + 256;        // slot 256..335
    bool s2v = (s2 < 324);
    int h1i = s1 / 9;
    int h2i = s2v ? s2 / 9 : 0;
    for (int p0 = r0; p0 < r1; p0 += 32) {
        int ne = min(32, r1 - p0);
        __syncthreads();
        for (int i = tid; i < ne * HEADS; i += 256) {
            wsh[i] = w[(size_t)p0 * HEADS + i] * inv[i % HEADS];
        }
        if (tid < ne) csh[tid] = col[p0 + tid];
        __syncthreads();
        int e = 0;
        for (; e + 2 <= ne; e += 2) {
            const ushort4* hA = (const ushort4*)(h1b + (size_t)csh[e] * HID);
            const ushort4* hB = (const ushort4*)(h1b + (size_t)csh[e + 1] * HID);
            ushort4 va1 = hA[s1];
            ushort4 vb1 = hB[s1];
            float wa = wsh[e * HEADS + h1i];
            float wb = wsh[(e + 1) * HEADS + h1i];
            acc0.x += wa * bf2f(va1.x) + wb * bf2f(vb1.x);
            acc0.y += wa * bf2f(va1.y) + wb * bf2f(vb1.y);
            acc0.z += wa * bf2f(va1.z) + wb * bf2f(vb1.z);
            acc0.w += wa * bf2f(va1.w) + wb * bf2f(vb1.w);
            if (s2v) {
                ushort4 va2 = hA[s2];
                ushort4 vb2 = hB[s2];
                float wa2 = wsh[e * HEADS + h2i];
                float wb2 = wsh[(e + 1) * HEADS + h2i];
                acc1.x += wa2 * bf2f(va2.x) + wb2 * bf2f(vb2.x);
                acc1.y += wa2 * bf2f(va2.y) + wb2 * bf2f(vb2.y);
                acc1.z += wa2 * bf2f(va2.z) + wb2 * bf2f(vb2.z);
                acc1.w += wa2 * bf2f(va2.w) + wb2 * bf2f(vb2.w);
            }
        }
        if (e < ne) {
            const ushort4* hA = (const ushort4*)(h1b + (size_t)csh[e] * HID);
            ushort4 va1 = hA[s1];
            float wa = wsh[e * HEADS + h1i];
            acc0.x += wa * bf2f(va1.x); acc0.y += wa * bf2f(va1.y);
            acc0.z += wa * bf2f(va1.z); acc0.w += wa * bf2f(va1.w);
            if (s2v) {
                ushort4 va2 = hA[s2];
                float wa2 = wsh[e * HEADS + h2i];
                acc1.x += wa2 * bf2f(va2.x); acc1.y += wa2 * bf2f(va2.y);
                acc1.z += wa2 * bf2f(va2.z); acc1.w += wa2 * bf2f(va2.w);
            }
        }
    }
    const float4* b4 = (const float4*)b1;
    ushort4* o4 = (ushort4*)(out1b + (size_t)n * KP2);
    {
        float4 bb = b4[s1];
        ushort4 o;
        o.x = f2bf(fmaxf(acc0.x + bb.x, 0.f)); o.y = f2bf(fmaxf(acc0.y + bb.y, 0.f));
        o.z = f2bf(fmaxf(acc0.z + bb.z, 0.f)); o.w = f2bf(fmaxf(acc0.w + bb.w, 0.f));
        o4[s1] = o;
    }
    if (s2v) {
        float4 bb = b4[s2];
        ushort4 o;
        o.x = f2bf(fmaxf(acc1.x + bb.x, 0.f)); o.y = f2bf(fmaxf(acc1.y + bb.y, 0.f));
        o.z = f2bf(fmaxf(acc1.z + bb.z, 0.f)); o.w = f2bf(fmaxf(acc1.w + bb.w, 0.f));
        o4[s2] = o;
    } else if (s2 < KP2 / 4) {
        o4[s2] = (ushort4){0, 0, 0, 0};   // zero K-pad for gemm2
    }
}

// ---------------- alpha2c: combine split-K halves -> bf16 h2 + per-node dots ----------------
__global__ __launch_bounds__(64) void k_alpha2c(const float* __restrict__ h2a,
                                                const float* __restrict__ h2b,
                                                unsigned short* __restrict__ h2q,
                                                const float* __restrict__ a_src,
                                                const float* __restrict__ a_dst,
                                                float* __restrict__ as,
                                                float* __restrict__ ad) {
    int n = blockIdx.x;
    int t = threadIdx.x;
    size_t base = (size_t)n * OUT_CH;
    float v0 = h2a[base + t] + h2b[base + t];
    float v1 = h2a[base + t + 64] + h2b[base + t + 64];
    h2q[base + t] = f2bf(v0);
    h2q[base + t + 64] = f2bf(v1);
    float ss = v0 * a_src[t] + v1 * a_src[t + 64];
    float sd = v0 * a_dst[t] + v1 * a_dst[t + 64];
    for (int off = 32; off > 0; off >>= 1) {
        ss += __shfl_down(ss, off);
        sd += __shfl_down(sd, off);
    }
    if (t == 0) { as[n] = ss; ad[n] = sd; }
}

// ---------------- agg2: bf16 gather, chunked weights, 64 threads (2 ch each) ----------------
__global__ __launch_bounds__(64) void k_agg2(const unsigned short* __restrict__ h2q,
                                             const float* __restrict__ as,
                                             const float* __restrict__ ad,
                                             const int* __restrict__ rowp,
                                             const int* __restrict__ col,
                                             const float* __restrict__ b2,
                                             float* __restrict__ out) {
    int n = blockIdx.x;
    int t = threadIdx.x;
    int r0 = rowp[n], r1 = rowp[n + 1];
    float adn = ad[n];
    float den = 0.f;
    for (int e = r0 + t; e < r1; e += 64) {
        float v = as[col[e]] + adn;
        v = (v > 0.f) ? v : NEG_SLOPE * v;
        den += __expf(v);
    }
#pragma unroll
    for (int off = 32; off > 0; off >>= 1) den += __shfl_xor(den, off);
    float inv = 1.f / (den + 1e-16f);
    __shared__ float wsh[32];
    __shared__ int csh[32];
    float acc0 = 0.f, acc1 = 0.f;
    for (int p0 = r0; p0 < r1; p0 += 32) {
        int ne = min(32, r1 - p0);
        __syncthreads();
        if (t < ne) {
            int s = col[p0 + t];
            csh[t] = s;
            float v = as[s] + adn;
            v = (v > 0.f) ? v : NEG_SLOPE * v;
            wsh[t] = __expf(v) * inv;
        }
        __syncthreads();
        int e = 0;
        for (; e + 2 <= ne; e += 2) {
            uint ua = *(const uint*)(h2q + (size_t)csh[e] * OUT_CH + t * 2);
            uint ub = *(const uint*)(h2q + (size_t)csh[e + 1] * OUT_CH + t * 2);
            float wa = wsh[e], wb = wsh[e + 1];
            acc0 += wa * bf2f((unsigned short)(ua & 0xFFFF)) + wb * bf2f((unsigned short)(ub & 0xFFFF));
            acc1 += wa * bf2f((unsigned short)(ua >> 16)) + wb * bf2f((unsigned short)(ub >> 16));
        }
        if (e < ne) {
            uint ua = *(const uint*)(h2q + (size_t)csh[e] * OUT_CH + t * 2);
            float wa = wsh[e];
            acc0 += wa * bf2f((unsigned short)(ua & 0xFFFF));
            acc1 += wa * bf2f((unsigned short)(ua >> 16));
        }
    }
    float o0 = acc0 + b2[t * 2];
    float o1 = acc1 + b2[t * 2 + 1];
    out[(size_t)n * OUT_CH + t * 2]     = (o0 > 0.f) ? o0 : 0.f;
    out[(size_t)n * OUT_CH + t * 2 + 1] = (o1 > 0.f) ? o1 : 0.f;
}

extern "C" void kernel_launch(void* const* d_in, const int* in_sizes, int n_in,
                              void* d_out, int out_size, void* d_ws, size_t ws_size,
                              hipStream_t stream) {
    const float* x      = (const float*)d_in[0];
    const int*   ei     = (const int*)d_in[1];
    const float* W1     = (const float*)d_in[2];
    const float* a_src1 = (const float*)d_in[3];
    const float* a_dst1 = (const float*)d_in[4];
    const float* b1     = (const float*)d_in[5];
    const float* W2     = (const float*)d_in[6];
    const float* a_src2 = (const float*)d_in[7];
    const float* a_dst2 = (const float*)d_in[8];
    const float* b2     = (const float*)d_in[9];
    float* out = (float*)d_out;

    // ---- workspace layout (cnt, cursor, den1 are one contiguous memset region) ----
    unsigned short* h1b   = (unsigned short*)d_ws;                 // 25,920,000 ush
    unsigned short* out1b = h1b + (size_t)N_NODES * HID;           // 26,880,000 ush
    unsigned short* xb    = out1b + (size_t)N_NODES * KP2;         // 2,560,000
    unsigned short* W1T   = xb + (size_t)N_NODES * IN_CH;          // 165,888
    unsigned short* W2T   = W1T + (size_t)HID * IN_CH;             // 172,032
    float* fbase = (float*)(W2T + NW2);
    float* as1  = fbase;                                           // 720,000
    float* ad1  = as1 + (size_t)N_NODES * HEADS;                   // 720,000
    float* wbuf = ad1 + (size_t)N_NODES * HEADS;                   // 6,480,000 (ET*HEADS)
    float* h2a  = wbuf;                                            // reuse after agg1 (2.56M)
    float* h2b  = wbuf + (size_t)N_NODES * OUT_CH;                 // 2.56M
    unsigned short* h2q = (unsigned short*)(wbuf + (size_t)2 * N_NODES * OUT_CH); // 2.56M ush
    float* as2  = wbuf + (size_t)ET * HEADS;                       // 20,000
    float* ad2  = as2 + N_NODES;                                   // 20,000
    int* cnt    = (int*)(ad2 + N_NODES);                           // 20,000 (memset region start)
    int* cursor = cnt + N_NODES;                                   // 20,000 (memset)
    float* den1 = (float*)(cursor + N_NODES);                      // 720,000 (memset)
    int* rowp   = (int*)(den1 + (size_t)N_NODES * HEADS);          // 20,001
    int* colx   = rowp + (N_NODES + 1);                            // 180,000
    int* dstn   = colx + ET;                                       // 180,000

    hipMemsetAsync(cnt, 0, (size_t)(2 * N_NODES + N_NODES * HEADS) * sizeof(int), stream);

    k_prep<<<(NX + NW1 + NW2 + 255) / 256, 256, 0, stream>>>(x, xb, W1, W1T, W2, W2T);
    k_count<<<(ET + 255) / 256, 256, 0, stream>>>(ei, cnt);
    k_scan<<<1, 1024, 0, stream>>>(cnt, rowp);
    k_fill<<<(ET + 255) / 256, 256, 0, stream>>>(ei, rowp, cursor, colx, dstn);
    k_gemm1<<<dim3(157, 21), 256, 0, stream>>>(xb, W1T, h1b);
    k_alpha1<<<(N_NODES * HEADS + 255) / 256, 256, 0, stream>>>(h1b, a_src1, a_dst1, as1, ad1);
    k_w1<<<(ET * HEADS + 255) / 256, 256, 0, stream>>>(as1, ad1, colx, dstn, wbuf, den1);
    k_agg1<<<N_NODES, 256, 0, stream>>>(h1b, wbuf, den1, rowp, colx, b1, out1b);
    k_gemm2<<<dim3(625, 2), 256, 0, stream>>>(out1b, W2T, h2a, h2b);
    k_alpha2c<<<N_NODES, 64, 0, stream>>>(h2a, h2b, h2q, a_src2, a_dst2, as2, ad2);
    k_agg2<<<N_NODES, 64, 0, stream>>>(h2q, as2, ad2, rowp, colx, b2, out);
}